// Round 5
// baseline (85814.716 us; speedup 1.0000x reference)
//
#include <hip/hip_runtime.h>

#define SP 514  // S + 2 (zero pad rows for K=3 'SAME' conv)

// ---------------------------------------------------------------------------
// Tiled f32 GEMM-BT: C[M=16384][N] = A[M][K] * Bt[N][K]^T (+bias | +=C).
// 64x64 tile, 256 threads, 4x4 per thread, LDS stride 33 (2-way conflicts are
// free per m136). OMODE 0 = store via (ldc, c_bstride, c_soff); 2 = mu scatter.
// ---------------------------------------------------------------------------
template <int OMODE, bool RELU, bool ACC>
__global__ __launch_bounds__(256) void gemm_f32(
    const float* __restrict__ A, int lda, long a_bstride, int a_soff,
    const float* __restrict__ Bt, int ldb,
    const float* __restrict__ bias,
    float* __restrict__ C, int ldc, long c_bstride, int c_soff,
    int N, int K)
{
  __shared__ float As[64][33];
  __shared__ float Bs[64][33];
  const int tid = threadIdx.x;
  const int tx = tid & 15, ty = tid >> 4;
  const int m0 = blockIdx.x * 64, n0 = blockIdx.y * 64;
  const int bb = m0 >> 9, ss = m0 & 511;
  const float* Abase = A + (size_t)bb * a_bstride + (size_t)(ss + a_soff) * lda;
  const int lr = tid >> 2, lc = (tid & 3) * 8;
  int rbn = n0 + lr; if (rbn > N - 1) rbn = N - 1;
  const float* ga = Abase + (size_t)lr * lda + lc;
  const float* gb = Bt + (size_t)rbn * ldb + lc;

  float acc[4][4];
#pragma unroll
  for (int i = 0; i < 4; i++)
#pragma unroll
    for (int j = 0; j < 4; j++) acc[i][j] = 0.f;

  for (int kt = 0; kt < K; kt += 32) {
    float4 a0 = *(const float4*)(ga + kt);
    float4 a1 = *(const float4*)(ga + kt + 4);
    float4 b0 = *(const float4*)(gb + kt);
    float4 b1 = *(const float4*)(gb + kt + 4);
    __syncthreads();                 // previous iteration's readers done
    As[lr][lc + 0] = a0.x; As[lr][lc + 1] = a0.y; As[lr][lc + 2] = a0.z; As[lr][lc + 3] = a0.w;
    As[lr][lc + 4] = a1.x; As[lr][lc + 5] = a1.y; As[lr][lc + 6] = a1.z; As[lr][lc + 7] = a1.w;
    Bs[lr][lc + 0] = b0.x; Bs[lr][lc + 1] = b0.y; Bs[lr][lc + 2] = b0.z; Bs[lr][lc + 3] = b0.w;
    Bs[lr][lc + 4] = b1.x; Bs[lr][lc + 5] = b1.y; Bs[lr][lc + 6] = b1.z; Bs[lr][lc + 7] = b1.w;
    __syncthreads();
#pragma unroll
    for (int kk = 0; kk < 32; kk++) {
      float av[4], bv[4];
#pragma unroll
      for (int i = 0; i < 4; i++) av[i] = As[ty * 4 + i][kk];
#pragma unroll
      for (int j = 0; j < 4; j++) bv[j] = Bs[tx * 4 + j][kk];
#pragma unroll
      for (int i = 0; i < 4; i++)
#pragma unroll
        for (int j = 0; j < 4; j++) acc[i][j] += av[i] * bv[j];
    }
  }

#pragma unroll
  for (int i = 0; i < 4; i++) {
    int m = m0 + ty * 4 + i;
    int b = m >> 9, s = m & 511;
#pragma unroll
    for (int j = 0; j < 4; j++) {
      int n = n0 + tx * 4 + j;
      if (n >= N) continue;
      float v;
      if (OMODE == 2) {
        v = acc[i][j] + bias[n];
        C[((size_t)(b * 80 + n)) * 512 + s] = v;
      } else {
        size_t idx = (size_t)b * (size_t)c_bstride + (size_t)(s + c_soff) * (size_t)ldc + n;
        if (ACC) v = acc[i][j] + C[idx];
        else     v = acc[i][j] + bias[n];
        if (RELU) v = fmaxf(v, 0.f);
        C[idx] = v;
      }
    }
  }
}

// naive f64-accum GEMM for the duration-predictor convs (small, precision-critical)
template <bool RELU>
__global__ __launch_bounds__(256) void ngemm64(
    const float* __restrict__ A, int lda, long a_bstride, int a_soff,
    const float* __restrict__ Bt, int ldb,
    const float* __restrict__ bias,
    float* __restrict__ C, int ldc, long c_bstride,
    int N, int K)
{
  int m = blockIdx.x;
  int n = blockIdx.y * 256 + threadIdx.x;
  if (n >= N) return;
  int b = m >> 9, s = m & 511;
  const float* ar = A + (size_t)b * a_bstride + (size_t)(s + a_soff) * lda;
  const float* br = Bt + (size_t)n * ldb;
  double acc = 0.0;
  for (int k = 0; k < K; k++) acc += (double)ar[k] * (double)br[k];
  double v = acc + (double)bias[n];
  if (RELU) v = v > 0.0 ? v : 0.0;
  C[(size_t)b * (size_t)c_bstride + (size_t)s * (size_t)ldc + n] = (float)v;
}

// ---------------------------------------------------------------------------
__global__ __launch_bounds__(256) void zero_padf(float* buf, int C) {
  int idx = blockIdx.x * 256 + threadIdx.x;
  int b = idx / (2 * C); int rem = idx % (2 * C);
  int which = rem / C; int c = rem % C;
  buf[((size_t)b * SP + (size_t)which * (SP - 1)) * C + c] = 0.f;
}

__global__ __launch_bounds__(256) void embedf(const int* __restrict__ ids,
                                              const float* __restrict__ emb,
                                              float* __restrict__ xpad) {
  int row = blockIdx.x; int tid = threadIdx.x;
  int b = row >> 9, s = row & 511;
  int tok = ids[row];
  size_t dst = (size_t)(b * SP + s + 1) * 512;
  const double scale = 22.627416997969522;  // sqrt(512)
  xpad[dst + tid]       = (float)((double)emb[(size_t)tok * 512 + tid] * scale);
  xpad[dst + tid + 256] = (float)((double)emb[(size_t)tok * 512 + tid + 256] * scale);
}

__global__ __launch_bounds__(256) void ropef(float* q, float* k) {
  int idx = blockIdx.x * 256 + threadIdx.x;
  int i = idx & 31;
  int h = (idx >> 5) & 7;
  int t = idx >> 8;          // b*512 + s
  int s = t & 511;
  size_t base = (size_t)t * 512 + h * 64;
  double theta = 1.0 / pow(10000.0, (double)i / 32.0);
  double ang = (double)s * theta;
  double sn, cs; sincos(ang, &sn, &cs);
  double x1 = q[base + i], x2 = q[base + i + 32];
  q[base + i]      = (float)(x1 * cs - x2 * sn);
  q[base + i + 32] = (float)(x2 * cs + x1 * sn);
  x1 = k[base + i]; x2 = k[base + i + 32];
  k[base + i]      = (float)(x1 * cs - x2 * sn);
  k[base + i + 32] = (float)(x2 * cs + x1 * sn);
}

// one wave per (b, head, q-row), two-pass softmax, f64 accumulation
__global__ __launch_bounds__(64) void nattf(const float* __restrict__ q, const float* __restrict__ k,
                                            const float* __restrict__ v, float* __restrict__ o,
                                            const int* __restrict__ lens) {
  int t = blockIdx.x;           // b*4096 + h*512 + s
  int s = t & 511, h = (t >> 9) & 7, b = t >> 12;
  int lane = threadIdx.x;
  int len = lens[b];
  __shared__ float qs[64];
  __shared__ float ps[512];
  size_t qoff = ((size_t)(b * 512 + s) * 512) + h * 64;
  qs[lane] = q[qoff + lane];
  __syncthreads();
  float sc[8];
  float mx = -1e30f;
#pragma unroll
  for (int jj = 0; jj < 8; jj++) {
    int kp = jj * 64 + lane;
    const float* kr = k + ((size_t)(b * 512 + kp) * 512) + h * 64;
    double dot = 0.0;
    for (int d = 0; d < 64; d++) dot += (double)qs[d] * (double)kr[d];
    sc[jj] = (kp >= len) ? (float)(dot * 0.125) : -1e9f;  // reference mask is inverted
    mx = fmaxf(mx, sc[jj]);
  }
  for (int off2 = 32; off2; off2 >>= 1) mx = fmaxf(mx, __shfl_down(mx, off2));
  mx = __shfl(mx, 0);
  double lsum = 0.0;
#pragma unroll
  for (int jj = 0; jj < 8; jj++) {
    float p = expf(sc[jj] - mx);
    ps[jj * 64 + lane] = p;
    lsum += (double)p;
  }
  for (int off2 = 32; off2; off2 >>= 1) lsum += __shfl_down(lsum, off2);
  lsum = __shfl(lsum, 0);
  __syncthreads();
  double acc = 0.0;
  for (int kp = 0; kp < 512; kp++)
    acc += (double)ps[kp] * (double)v[((size_t)(b * 512 + kp) * 512) + h * 64 + lane];
  o[qoff + lane] = (float)(acc / lsum);
}

// LayerNorm(xpad + t) over 512; two-pass (mean, then E[(x-m)^2]) in f64
__global__ __launch_bounds__(256) void ln_resf(float* xpad, const float* __restrict__ t,
                                               const float* __restrict__ g, const float* __restrict__ be) {
  int row = blockIdx.x, tid = threadIdx.x;
  int b = row >> 9, s = row & 511;
  size_t pb_ = (size_t)(b * SP + s + 1) * 512;
  size_t tb = (size_t)row * 512;
  double v0 = (double)xpad[pb_ + tid] + (double)t[tb + tid];
  double v1 = (double)xpad[pb_ + tid + 256] + (double)t[tb + tid + 256];
  __shared__ double red[4];
  int w = tid >> 6, lane = tid & 63;
  double sum = v0 + v1;
  for (int o = 32; o; o >>= 1) sum += __shfl_down(sum, o);
  if (!lane) red[w] = sum;
  __syncthreads();
  double mean = (red[0] + red[1] + red[2] + red[3]) * (1.0 / 512.0);
  __syncthreads();
  double d0 = v0 - mean, d1 = v1 - mean;
  double sq = d0 * d0 + d1 * d1;
  for (int o = 32; o; o >>= 1) sq += __shfl_down(sq, o);
  if (!lane) red[w] = sq;
  __syncthreads();
  double var = (red[0] + red[1] + red[2] + red[3]) * (1.0 / 512.0);
  double inv = 1.0 / sqrt(var + 1e-5);
  xpad[pb_ + tid]       = (float)(d0 * inv * (double)g[tid] + (double)be[tid]);
  xpad[pb_ + tid + 256] = (float)(d1 * inv * (double)g[tid + 256] + (double)be[tid + 256]);
}

// dp LayerNorm over 256 (input f32 scratch, relu+mask applied), writes padded f32
__global__ __launch_bounds__(256) void dplnf(const float* __restrict__ t, float* __restrict__ outp,
                                             const float* __restrict__ g, const float* __restrict__ be,
                                             const int* __restrict__ lens) {
  int row = blockIdx.x, tid = threadIdx.x;
  int b = row >> 9, s = row & 511;
  double mval = (s >= lens[b]) ? 1.0 : 0.0;
  double v = fmax((double)t[(size_t)row * 256 + tid], 0.0) * mval;
  __shared__ double red[4];
  int w = tid >> 6, lane = tid & 63;
  double sum = v;
  for (int o = 32; o; o >>= 1) sum += __shfl_down(sum, o);
  if (!lane) red[w] = sum;
  __syncthreads();
  double mean = (red[0] + red[1] + red[2] + red[3]) * (1.0 / 256.0);
  __syncthreads();
  double d = v - mean;
  double sq = d * d;
  for (int o = 32; o; o >>= 1) sq += __shfl_down(sq, o);
  if (!lane) red[w] = sq;
  __syncthreads();
  double var = (red[0] + red[1] + red[2] + red[3]) * (1.0 / 256.0);
  double inv = 1.0 / sqrt(var + 1e-5);
  outp[(size_t)(b * SP + s + 1) * 256 + tid] = (float)(d * inv * (double)g[tid] + (double)be[tid]);
}

__global__ __launch_bounds__(256) void maskhf(const float* __restrict__ xpad, float* __restrict__ hm,
                                              const int* __restrict__ lens) {
  int row = blockIdx.x, tid = threadIdx.x;
  int b = row >> 9, s = row & 511;
  float keep = (s >= lens[b]) ? 1.f : 0.f;
  size_t off = (size_t)(b * SP + s + 1) * 512;
  hm[off + tid]       = xpad[off + tid] * keep;
  hm[off + tid + 256] = xpad[off + tid + 256] * keep;
}

// conv1-weight repack: dst[f'][k*512+c] = c1w[l][foff+f'][c][k]   (1024x1536)
__global__ __launch_bounds__(256) void repack1(const float* __restrict__ src, float* __restrict__ dst,
                                               int l, int foff) {
  int idx = blockIdx.x * 256 + threadIdx.x;       // < 1024*1536
  int f = idx / 1536, kk = idx % 1536;
  int k = kk / 512, c = kk % 512;
  dst[idx] = src[(((size_t)(l * 2048 + foff + f)) * 512 + c) * 3 + k];
}
// conv2-weight repack: dst[o][k*1024+c'] = c2w[l][o][coff+c'][k]   (512x3072)
__global__ __launch_bounds__(256) void repack2(const float* __restrict__ src, float* __restrict__ dst,
                                               int l, int coff) {
  int idx = blockIdx.x * 256 + threadIdx.x;       // < 512*3072
  int o = idx / 3072, kk = idx % 3072;
  int k = kk / 1024, c = kk % 1024;
  dst[idx] = src[(((size_t)(l * 512 + o)) * 2048 + coff + c) * 3 + k];
}
// dp conv repacks
__global__ __launch_bounds__(256) void repack_dp1(const float* __restrict__ src, float* __restrict__ dst) {
  int idx = blockIdx.x * 256 + threadIdx.x;       // < 256*1536
  int f = idx / 1536, kk = idx % 1536;
  int k = kk / 512, c = kk % 512;
  dst[idx] = src[((size_t)f * 512 + c) * 3 + k];
}
__global__ __launch_bounds__(256) void repack_dp2(const float* __restrict__ src, float* __restrict__ dst) {
  int idx = blockIdx.x * 256 + threadIdx.x;       // < 256*768
  int f = idx / 768, kk = idx % 768;
  int k = kk / 256, c = kk % 256;
  dst[idx] = src[((size_t)f * 256 + c) * 3 + k];
}

__global__ __launch_bounds__(256) void dur_kf(const float* __restrict__ dp3, const float* __restrict__ pw,
                                              const float* __restrict__ pb, const int* __restrict__ lens,
                                              float* __restrict__ out) {
  int tid = threadIdx.x;
  int w = tid >> 6, lane = tid & 63;
  int row = blockIdx.x * 4 + w;
  int b = row >> 9, s = row & 511;
  size_t base = (size_t)(b * SP + s + 1) * 256;
  double sum = 0.0;
#pragma unroll
  for (int e = 0; e < 4; e++) {
    int c = lane + 64 * e;
    sum += (double)dp3[base + c] * (double)pw[c];
  }
  for (int o = 32; o; o >>= 1) sum += __shfl_down(sum, o);
  if (lane == 0) {
    double y = sum + (double)pb[0];
    double mval = (s >= lens[b]) ? 1.0 : 0.0;
    y *= mval;
    out[row] = (float)ceil(exp(y));
  }
}

// ---------------------------------------------------------------------------
extern "C" void kernel_launch(void* const* d_in, const int* in_sizes, int n_in,
                              void* d_out, int out_size, void* d_ws, size_t ws_size,
                              hipStream_t stream) {
  const int* xids = (const int*)d_in[0];
  const int* lens = (const int*)d_in[1];
  const float* emb  = (const float*)d_in[2];
  const float* Wq = (const float*)d_in[3];  const float* bq = (const float*)d_in[4];
  const float* Wk = (const float*)d_in[5];  const float* bk = (const float*)d_in[6];
  const float* Wv = (const float*)d_in[7];  const float* bv = (const float*)d_in[8];
  const float* Wo = (const float*)d_in[9];  const float* bo = (const float*)d_in[10];
  const float* c1w = (const float*)d_in[11]; const float* c1b = (const float*)d_in[12];
  const float* c2w = (const float*)d_in[13]; const float* c2b = (const float*)d_in[14];
  const float* ln1g = (const float*)d_in[15]; const float* ln1b = (const float*)d_in[16];
  const float* ln2g = (const float*)d_in[17]; const float* ln2b = (const float*)d_in[18];
  const float* pw = (const float*)d_in[19];  const float* pb = (const float*)d_in[20];
  const float* dpc1w = (const float*)d_in[21]; const float* dpc1b = (const float*)d_in[22];
  const float* dpln1g = (const float*)d_in[23]; const float* dpln1b = (const float*)d_in[24];
  const float* dpc2w = (const float*)d_in[25]; const float* dpc2b = (const float*)d_in[26];
  const float* dpln2g = (const float*)d_in[27]; const float* dpln2b = (const float*)d_in[28];
  const float* dppw = (const float*)d_in[29]; const float* dppb = (const float*)d_in[30];
  float* out = (float*)d_out;

  char* p = (char*)d_ws;
  float* xpad = (float*)p;  p += 33685504;   // (B,SP,512) f32
  float* qb = (float*)p;    p += 33554432;   // (B,S,512)
  float* kb = (float*)p;    p += 33554432;   //  -- doubles as t / dp scratch
  float* vb = (float*)p;    p += 33554432;
  float* midf = (float*)p;  p += 67371008;   // (B,SP,1024) conv half; aliased by dp stage
  float* w1t = (float*)p;   p += 6291456;    // (1024,1536)
  float* w2t = (float*)p;   p += 6291456;    // (512,3072)
  float* dpw1t = (float*)p; p += 1572864;    // (256,1536)
  float* dpw2t = (float*)p; p += 786432;     // (256,768)
  // dp-stage aliases of midf (layers done before dp stage)
  float* hm  = midf;                                   // (B,SP,512)
  float* dp2 = (float*)((char*)midf + 33685504);       // (B,SP,256)
  float* dp3 = (float*)((char*)midf + 33685504 + 16842752);

  zero_padf<<<128, 256, 0, stream>>>(xpad, 512);
  zero_padf<<<256, 256, 0, stream>>>(midf, 1024);
  embedf<<<16384, 256, 0, stream>>>(xids, emb, xpad);

  const long XB = (long)SP * 512;     // xpad batch stride
  const long QB = (long)512 * 512;    // qkv/t batch stride
  const long MB = (long)SP * 1024;    // midf batch stride

  for (int l = 0; l < 6; l++) {
    gemm_f32<0, false, false><<<dim3(256, 8), 256, 0, stream>>>(
        xpad, 512, XB, 1, Wq + (size_t)l * 262144, 512, bq + l * 512,
        qb, 512, QB, 0, 512, 512);
    gemm_f32<0, false, false><<<dim3(256, 8), 256, 0, stream>>>(
        xpad, 512, XB, 1, Wk + (size_t)l * 262144, 512, bk + l * 512,
        kb, 512, QB, 0, 512, 512);
    gemm_f32<0, false, false><<<dim3(256, 8), 256, 0, stream>>>(
        xpad, 512, XB, 1, Wv + (size_t)l * 262144, 512, bv + l * 512,
        vb, 512, QB, 0, 512, 512);
    ropef<<<16384, 256, 0, stream>>>(qb, kb);
    nattf<<<131072, 64, 0, stream>>>(qb, kb, vb, qb, lens);   // o in-place over q
    gemm_f32<0, false, false><<<dim3(256, 8), 256, 0, stream>>>(
        qb, 512, QB, 0, Wo + (size_t)l * 262144, 512, bo + l * 512,
        kb, 512, QB, 0, 512, 512);                             // t -> kb
    ln_resf<<<16384, 256, 0, stream>>>(xpad, kb, ln1g + l * 512, ln1b + l * 512);
    // conv FFN in two output/input-channel halves (midf holds one half)
    repack1<<<6144, 256, 0, stream>>>(c1w, w1t, l, 0);
    gemm_f32<0, true, false><<<dim3(256, 16), 256, 0, stream>>>(
        xpad, 512, XB, 0, w1t, 1536, c1b + l * 2048 + 0,
        midf, 1024, MB, 1, 1024, 1536);
    repack2<<<6144, 256, 0, stream>>>(c2w, w2t, l, 0);
    gemm_f32<0, false, false><<<dim3(256, 8), 256, 0, stream>>>(
        midf, 1024, MB, 0, w2t, 3072, c2b + l * 512,
        kb, 512, QB, 0, 512, 3072);
    repack1<<<6144, 256, 0, stream>>>(c1w, w1t, l, 1024);
    gemm_f32<0, true, false><<<dim3(256, 16), 256, 0, stream>>>(
        xpad, 512, XB, 0, w1t, 1536, c1b + l * 2048 + 1024,
        midf, 1024, MB, 1, 1024, 1536);
    repack2<<<6144, 256, 0, stream>>>(c2w, w2t, l, 1024);
    gemm_f32<0, false, true><<<dim3(256, 8), 256, 0, stream>>>(
        midf, 1024, MB, 0, w2t, 3072, c2b + l * 512,
        kb, 512, QB, 0, 512, 3072);
    ln_resf<<<16384, 256, 0, stream>>>(xpad, kb, ln2g + l * 512, ln2b + l * 512);
  }

  // mu projection: N=80, scatter to (B,80,S) f32
  gemm_f32<2, false, false><<<dim3(256, 2), 256, 0, stream>>>(
      xpad, 512, XB, 1, pw, 512, pb, out, 0, 0, 0, 80, 512);

  // duration predictor (f64-accum convs, f64 LN)
  zero_padf<<<128, 256, 0, stream>>>(hm, 512);
  zero_padf<<<64, 256, 0, stream>>>(dp2, 256);
  zero_padf<<<64, 256, 0, stream>>>(dp3, 256);
  maskhf<<<16384, 256, 0, stream>>>(xpad, hm, lens);
  repack_dp1<<<1536, 256, 0, stream>>>(dpc1w, dpw1t);
  repack_dp2<<<768, 256, 0, stream>>>(dpc2w, dpw2t);
  ngemm64<true><<<dim3(16384, 1), 256, 0, stream>>>(
      hm, 512, XB, 0, dpw1t, 1536, dpc1b, kb, 256, (long)512 * 256, 256, 1536);
  dplnf<<<16384, 256, 0, stream>>>(kb, dp2, dpln1g, dpln1b, lens);
  ngemm64<true><<<dim3(16384, 1), 256, 0, stream>>>(
      dp2, 256, (long)SP * 256, 0, dpw2t, 768, dpc2b, kb, 256, (long)512 * 256, 256, 768);
  dplnf<<<16384, 256, 0, stream>>>(kb, dp3, dpln2g, dpln2b, lens);
  dur_kf<<<4096, 256, 0, stream>>>(dp3, dppw, dppb, lens, out + 1310720);
}

// Round 6
// 33391.647 us; speedup vs baseline: 2.5699x; 2.5699x over previous
//
#include <hip/hip_runtime.h>

#define SP 514  // S + 2 (zero pad rows for K=3 'SAME' conv)

// ---------------------------------------------------------------------------
// Tiled f32 GEMM-BT: C[M=16384][N] = A[M][K] * Bt[N][K]^T (+bias | +=C).
// 64x64 tile, 256 threads, 4x4 per thread, LDS stride 33.
// OMODE 0 = store via (ldc, c_bstride, c_soff); 2 = mu scatter.
// ---------------------------------------------------------------------------
template <int OMODE, bool RELU, bool ACC>
__global__ __launch_bounds__(256) void gemm_f32(
    const float* __restrict__ A, int lda, long a_bstride, int a_soff,
    const float* __restrict__ Bt, int ldb,
    const float* __restrict__ bias,
    float* __restrict__ C, int ldc, long c_bstride, int c_soff,
    int N, int K)
{
  __shared__ float As[64][33];
  __shared__ float Bs[64][33];
  const int tid = threadIdx.x;
  const int tx = tid & 15, ty = tid >> 4;
  const int m0 = blockIdx.x * 64, n0 = blockIdx.y * 64;
  const int bb = m0 >> 9, ss = m0 & 511;
  const float* Abase = A + (size_t)bb * a_bstride + (size_t)(ss + a_soff) * lda;
  const int lr = tid >> 2, lc = (tid & 3) * 8;
  int rbn = n0 + lr; if (rbn > N - 1) rbn = N - 1;
  const float* ga = Abase + (size_t)lr * lda + lc;
  const float* gb = Bt + (size_t)rbn * ldb + lc;

  float acc[4][4];
#pragma unroll
  for (int i = 0; i < 4; i++)
#pragma unroll
    for (int j = 0; j < 4; j++) acc[i][j] = 0.f;

  for (int kt = 0; kt < K; kt += 32) {
    float4 a0 = *(const float4*)(ga + kt);
    float4 a1 = *(const float4*)(ga + kt + 4);
    float4 b0 = *(const float4*)(gb + kt);
    float4 b1 = *(const float4*)(gb + kt + 4);
    __syncthreads();
    As[lr][lc + 0] = a0.x; As[lr][lc + 1] = a0.y; As[lr][lc + 2] = a0.z; As[lr][lc + 3] = a0.w;
    As[lr][lc + 4] = a1.x; As[lr][lc + 5] = a1.y; As[lr][lc + 6] = a1.z; As[lr][lc + 7] = a1.w;
    Bs[lr][lc + 0] = b0.x; Bs[lr][lc + 1] = b0.y; Bs[lr][lc + 2] = b0.z; Bs[lr][lc + 3] = b0.w;
    Bs[lr][lc + 4] = b1.x; Bs[lr][lc + 5] = b1.y; Bs[lr][lc + 6] = b1.z; Bs[lr][lc + 7] = b1.w;
    __syncthreads();
#pragma unroll
    for (int kk = 0; kk < 32; kk++) {
      float av[4], bv[4];
#pragma unroll
      for (int i = 0; i < 4; i++) av[i] = As[ty * 4 + i][kk];
#pragma unroll
      for (int j = 0; j < 4; j++) bv[j] = Bs[tx * 4 + j][kk];
#pragma unroll
      for (int i = 0; i < 4; i++)
#pragma unroll
        for (int j = 0; j < 4; j++) acc[i][j] += av[i] * bv[j];
    }
  }

#pragma unroll
  for (int i = 0; i < 4; i++) {
    int m = m0 + ty * 4 + i;
    int b = m >> 9, s = m & 511;
#pragma unroll
    for (int j = 0; j < 4; j++) {
      int n = n0 + tx * 4 + j;
      if (n >= N) continue;
      float v;
      if (OMODE == 2) {
        v = acc[i][j] + bias[n];
        C[((size_t)(b * 80 + n)) * 512 + s] = v;
      } else {
        size_t idx = (size_t)b * (size_t)c_bstride + (size_t)(s + c_soff) * (size_t)ldc + n;
        if (ACC) v = acc[i][j] + C[idx];
        else     v = acc[i][j] + bias[n];
        if (RELU) v = fmaxf(v, 0.f);
        C[idx] = v;
      }
    }
  }
}

// ---------------------------------------------------------------------------
// Tiled dp-conv GEMM, f64 accumulation in identical k-order to round-5's
// ngemm64 (bit-compatible with the passing durations output), but with LDS
// tiling so it is throughput- not latency-bound.
// ---------------------------------------------------------------------------
template <bool RELU>
__global__ __launch_bounds__(256) void gemm_dp64(
    const float* __restrict__ A, int lda, long a_bstride, int a_soff,
    const float* __restrict__ Bt, int ldb,
    const float* __restrict__ bias,
    float* __restrict__ C, int ldc, long c_bstride,
    int N, int K)
{
  __shared__ float As[64][33];
  __shared__ float Bs[64][33];
  const int tid = threadIdx.x;
  const int tx = tid & 15, ty = tid >> 4;
  const int m0 = blockIdx.x * 64, n0 = blockIdx.y * 64;
  const int bb = m0 >> 9, ss = m0 & 511;
  const float* Abase = A + (size_t)bb * a_bstride + (size_t)(ss + a_soff) * lda;
  const int lr = tid >> 2, lc = (tid & 3) * 8;
  int rbn = n0 + lr; if (rbn > N - 1) rbn = N - 1;
  const float* ga = Abase + (size_t)lr * lda + lc;
  const float* gb = Bt + (size_t)rbn * ldb + lc;

  double acc[4][4];
#pragma unroll
  for (int i = 0; i < 4; i++)
#pragma unroll
    for (int j = 0; j < 4; j++) acc[i][j] = 0.0;

  for (int kt = 0; kt < K; kt += 32) {
    float4 a0 = *(const float4*)(ga + kt);
    float4 a1 = *(const float4*)(ga + kt + 4);
    float4 b0 = *(const float4*)(gb + kt);
    float4 b1 = *(const float4*)(gb + kt + 4);
    __syncthreads();
    As[lr][lc + 0] = a0.x; As[lr][lc + 1] = a0.y; As[lr][lc + 2] = a0.z; As[lr][lc + 3] = a0.w;
    As[lr][lc + 4] = a1.x; As[lr][lc + 5] = a1.y; As[lr][lc + 6] = a1.z; As[lr][lc + 7] = a1.w;
    Bs[lr][lc + 0] = b0.x; Bs[lr][lc + 1] = b0.y; Bs[lr][lc + 2] = b0.z; Bs[lr][lc + 3] = b0.w;
    Bs[lr][lc + 4] = b1.x; Bs[lr][lc + 5] = b1.y; Bs[lr][lc + 6] = b1.z; Bs[lr][lc + 7] = b1.w;
    __syncthreads();
#pragma unroll
    for (int kk = 0; kk < 32; kk++) {
      double av[4], bv[4];
#pragma unroll
      for (int i = 0; i < 4; i++) av[i] = (double)As[ty * 4 + i][kk];
#pragma unroll
      for (int j = 0; j < 4; j++) bv[j] = (double)Bs[tx * 4 + j][kk];
#pragma unroll
      for (int i = 0; i < 4; i++)
#pragma unroll
        for (int j = 0; j < 4; j++) acc[i][j] += av[i] * bv[j];
    }
  }

#pragma unroll
  for (int i = 0; i < 4; i++) {
    int m = m0 + ty * 4 + i;
    int b = m >> 9, s = m & 511;
#pragma unroll
    for (int j = 0; j < 4; j++) {
      int n = n0 + tx * 4 + j;
      if (n >= N) continue;
      double v = acc[i][j] + (double)bias[n];
      if (RELU) v = v > 0.0 ? v : 0.0;
      C[(size_t)b * (size_t)c_bstride + (size_t)s * (size_t)ldc + n] = (float)v;
    }
  }
}

// ---------------------------------------------------------------------------
// Flash attention, f32: one block per (b, head, 64-row q tile), online softmax.
// o written in-place over q (each block owns its (rows, head-cols) region).
// ---------------------------------------------------------------------------
__global__ __launch_bounds__(256) void flashf(const float* __restrict__ q, const float* __restrict__ k,
                                              const float* __restrict__ v, float* __restrict__ o,
                                              const int* __restrict__ lens) {
  int blk = blockIdx.x;
  int qt = blk & 7, h = (blk >> 3) & 7, b = blk >> 6;
  int q0 = qt * 64;
  int len = lens[b];
  __shared__ float Qs[64][68], Ks[64][68], Vs[64][68], Ps[64][68];
  __shared__ float mL[64], lL[64], aL[64];
  __shared__ float psum[64][17];
  int tid = threadIdx.x;
  int tx = tid & 15, ty = tid >> 4;
  int r0 = ty * 4, c0 = tx * 4;
  {
    int r = tid >> 2, cc = (tid & 3) * 16;
    const float* src = q + ((size_t)(b * 512 + q0 + r) * 512) + h * 64 + cc;
#pragma unroll
    for (int e = 0; e < 16; e += 4) {
      float4 t4 = *(const float4*)(src + e);
      Qs[r][cc + e] = t4.x; Qs[r][cc + e + 1] = t4.y; Qs[r][cc + e + 2] = t4.z; Qs[r][cc + e + 3] = t4.w;
    }
  }
  if (tid < 64) { mL[tid] = -1e30f; lL[tid] = 0.f; }
  float o_acc[4][4];
#pragma unroll
  for (int i = 0; i < 4; i++)
#pragma unroll
    for (int j = 0; j < 4; j++) o_acc[i][j] = 0.f;

  for (int kc = 0; kc < 8; kc++) {
    int kbase = kc * 64;
    __syncthreads();          // prev-iter readers done before overwriting Ks/Vs
    {
      int r = tid >> 2, cc = (tid & 3) * 16;
      const float* ks = k + ((size_t)(b * 512 + kbase + r) * 512) + h * 64 + cc;
      const float* vs = v + ((size_t)(b * 512 + kbase + r) * 512) + h * 64 + cc;
#pragma unroll
      for (int e = 0; e < 16; e += 4) {
        float4 a4 = *(const float4*)(ks + e);
        float4 b4 = *(const float4*)(vs + e);
        Ks[r][cc + e] = a4.x; Ks[r][cc + e + 1] = a4.y; Ks[r][cc + e + 2] = a4.z; Ks[r][cc + e + 3] = a4.w;
        Vs[r][cc + e] = b4.x; Vs[r][cc + e + 1] = b4.y; Vs[r][cc + e + 2] = b4.z; Vs[r][cc + e + 3] = b4.w;
      }
    }
    __syncthreads();
    float sacc[4][4];
#pragma unroll
    for (int i = 0; i < 4; i++)
#pragma unroll
      for (int j = 0; j < 4; j++) sacc[i][j] = 0.f;
#pragma unroll
    for (int kk = 0; kk < 64; kk += 4) {
      float4 qv[4], kv[4];
#pragma unroll
      for (int i = 0; i < 4; i++) qv[i] = *(const float4*)&Qs[r0 + i][kk];
#pragma unroll
      for (int j = 0; j < 4; j++) kv[j] = *(const float4*)&Ks[c0 + j][kk];
#pragma unroll
      for (int i = 0; i < 4; i++)
#pragma unroll
        for (int j = 0; j < 4; j++)
          sacc[i][j] += qv[i].x * kv[j].x + qv[i].y * kv[j].y + qv[i].z * kv[j].z + qv[i].w * kv[j].w;
    }
    // reference mask is inverted: KEEP score where s_k >= len, else -1e9
#pragma unroll
    for (int i = 0; i < 4; i++)
#pragma unroll
      for (int j = 0; j < 4; j++) {
        int kg = kbase + c0 + j;
        Ps[r0 + i][c0 + j] = (kg >= len) ? sacc[i][j] * 0.125f : -1e9f;
      }
    __syncthreads();
    if (tid < 64) {
      float m_old = mL[tid];
      float mx = m_old;
      for (int c = 0; c < 64; c++) mx = fmaxf(mx, Ps[tid][c]);
      float alpha = expf(m_old - mx);
      mL[tid] = mx; aL[tid] = alpha; lL[tid] *= alpha;
    }
    __syncthreads();
    float ps4[4] = {0.f, 0.f, 0.f, 0.f};
#pragma unroll
    for (int i = 0; i < 4; i++) {
      float mrow = mL[r0 + i];
#pragma unroll
      for (int j = 0; j < 4; j++) {
        float pp = expf(Ps[r0 + i][c0 + j] - mrow);
        Ps[r0 + i][c0 + j] = pp;
        ps4[i] += pp;
      }
    }
#pragma unroll
    for (int i = 0; i < 4; i++) psum[r0 + i][tx] = ps4[i];
    __syncthreads();
    if (tid < 64) {
      float accl = 0.f;
      for (int t2 = 0; t2 < 16; t2++) accl += psum[tid][t2];
      lL[tid] += accl;
    }
#pragma unroll
    for (int i = 0; i < 4; i++) {
      float a = aL[r0 + i];
#pragma unroll
      for (int j = 0; j < 4; j++) o_acc[i][j] *= a;
    }
#pragma unroll
    for (int kk = 0; kk < 64; kk += 4) {
      float4 pv[4], vv[4];
#pragma unroll
      for (int i = 0; i < 4; i++) pv[i] = *(const float4*)&Ps[r0 + i][kk];
#pragma unroll
      for (int t2 = 0; t2 < 4; t2++) vv[t2] = *(const float4*)&Vs[kk + t2][c0];
#pragma unroll
      for (int i = 0; i < 4; i++) {
        o_acc[i][0] += pv[i].x * vv[0].x + pv[i].y * vv[1].x + pv[i].z * vv[2].x + pv[i].w * vv[3].x;
        o_acc[i][1] += pv[i].x * vv[0].y + pv[i].y * vv[1].y + pv[i].z * vv[2].y + pv[i].w * vv[3].y;
        o_acc[i][2] += pv[i].x * vv[0].z + pv[i].y * vv[1].z + pv[i].z * vv[2].z + pv[i].w * vv[3].z;
        o_acc[i][3] += pv[i].x * vv[0].w + pv[i].y * vv[1].w + pv[i].z * vv[2].w + pv[i].w * vv[3].w;
      }
    }
  }
  __syncthreads();
#pragma unroll
  for (int i = 0; i < 4; i++) {
    float invl = 1.f / lL[r0 + i];
    size_t base = (size_t)(b * 512 + q0 + r0 + i) * 512 + h * 64 + c0;
#pragma unroll
    for (int j = 0; j < 4; j++) o[base + j] = o_acc[i][j] * invl;
  }
}

// ---------------------------------------------------------------------------
__global__ __launch_bounds__(256) void zero_padf(float* buf, int C) {
  int idx = blockIdx.x * 256 + threadIdx.x;
  int b = idx / (2 * C); int rem = idx % (2 * C);
  int which = rem / C; int c = rem % C;
  buf[((size_t)b * SP + (size_t)which * (SP - 1)) * C + c] = 0.f;
}

__global__ __launch_bounds__(256) void embedf(const int* __restrict__ ids,
                                              const float* __restrict__ emb,
                                              float* __restrict__ xpad) {
  int row = blockIdx.x; int tid = threadIdx.x;
  int b = row >> 9, s = row & 511;
  int tok = ids[row];
  size_t dst = (size_t)(b * SP + s + 1) * 512;
  const double scale = 22.627416997969522;  // sqrt(512)
  xpad[dst + tid]       = (float)((double)emb[(size_t)tok * 512 + tid] * scale);
  xpad[dst + tid + 256] = (float)((double)emb[(size_t)tok * 512 + tid + 256] * scale);
}

__global__ __launch_bounds__(256) void ropef(float* q, float* k) {
  int idx = blockIdx.x * 256 + threadIdx.x;
  int i = idx & 31;
  int h = (idx >> 5) & 7;
  int t = idx >> 8;          // b*512 + s
  int s = t & 511;
  size_t base = (size_t)t * 512 + h * 64;
  double theta = 1.0 / pow(10000.0, (double)i / 32.0);
  double ang = (double)s * theta;
  double sn, cs; sincos(ang, &sn, &cs);
  double x1 = q[base + i], x2 = q[base + i + 32];
  q[base + i]      = (float)(x1 * cs - x2 * sn);
  q[base + i + 32] = (float)(x2 * cs + x1 * sn);
  x1 = k[base + i]; x2 = k[base + i + 32];
  k[base + i]      = (float)(x1 * cs - x2 * sn);
  k[base + i + 32] = (float)(x2 * cs + x1 * sn);
}

// LayerNorm(xpad + t) over 512; two-pass in f64
__global__ __launch_bounds__(256) void ln_resf(float* xpad, const float* __restrict__ t,
                                               const float* __restrict__ g, const float* __restrict__ be) {
  int row = blockIdx.x, tid = threadIdx.x;
  int b = row >> 9, s = row & 511;
  size_t pb_ = (size_t)(b * SP + s + 1) * 512;
  size_t tb = (size_t)row * 512;
  double v0 = (double)xpad[pb_ + tid] + (double)t[tb + tid];
  double v1 = (double)xpad[pb_ + tid + 256] + (double)t[tb + tid + 256];
  __shared__ double red[4];
  int w = tid >> 6, lane = tid & 63;
  double sum = v0 + v1;
  for (int o = 32; o; o >>= 1) sum += __shfl_down(sum, o);
  if (!lane) red[w] = sum;
  __syncthreads();
  double mean = (red[0] + red[1] + red[2] + red[3]) * (1.0 / 512.0);
  __syncthreads();
  double d0 = v0 - mean, d1 = v1 - mean;
  double sq = d0 * d0 + d1 * d1;
  for (int o = 32; o; o >>= 1) sq += __shfl_down(sq, o);
  if (!lane) red[w] = sq;
  __syncthreads();
  double var = (red[0] + red[1] + red[2] + red[3]) * (1.0 / 512.0);
  double inv = 1.0 / sqrt(var + 1e-5);
  xpad[pb_ + tid]       = (float)(d0 * inv * (double)g[tid] + (double)be[tid]);
  xpad[pb_ + tid + 256] = (float)(d1 * inv * (double)g[tid + 256] + (double)be[tid + 256]);
}

__global__ __launch_bounds__(256) void dplnf(const float* __restrict__ t, float* __restrict__ outp,
                                             const float* __restrict__ g, const float* __restrict__ be,
                                             const int* __restrict__ lens) {
  int row = blockIdx.x, tid = threadIdx.x;
  int b = row >> 9, s = row & 511;
  double mval = (s >= lens[b]) ? 1.0 : 0.0;
  double v = fmax((double)t[(size_t)row * 256 + tid], 0.0) * mval;
  __shared__ double red[4];
  int w = tid >> 6, lane = tid & 63;
  double sum = v;
  for (int o = 32; o; o >>= 1) sum += __shfl_down(sum, o);
  if (!lane) red[w] = sum;
  __syncthreads();
  double mean = (red[0] + red[1] + red[2] + red[3]) * (1.0 / 256.0);
  __syncthreads();
  double d = v - mean;
  double sq = d * d;
  for (int o = 32; o; o >>= 1) sq += __shfl_down(sq, o);
  if (!lane) red[w] = sq;
  __syncthreads();
  double var = (red[0] + red[1] + red[2] + red[3]) * (1.0 / 256.0);
  double inv = 1.0 / sqrt(var + 1e-5);
  outp[(size_t)(b * SP + s + 1) * 256 + tid] = (float)(d * inv * (double)g[tid] + (double)be[tid]);
}

__global__ __launch_bounds__(256) void maskhf(const float* __restrict__ xpad, float* __restrict__ hm,
                                              const int* __restrict__ lens) {
  int row = blockIdx.x, tid = threadIdx.x;
  int b = row >> 9, s = row & 511;
  float keep = (s >= lens[b]) ? 1.f : 0.f;
  size_t off = (size_t)(b * SP + s + 1) * 512;
  hm[off + tid]       = xpad[off + tid] * keep;
  hm[off + tid + 256] = xpad[off + tid + 256] * keep;
}

// conv1-weight repack: dst[f'][k*512+c] = c1w[l][foff+f'][c][k]   (1024x1536)
__global__ __launch_bounds__(256) void repack1(const float* __restrict__ src, float* __restrict__ dst,
                                               int l, int foff) {
  int idx = blockIdx.x * 256 + threadIdx.x;
  int f = idx / 1536, kk = idx % 1536;
  int k = kk / 512, c = kk % 512;
  dst[idx] = src[(((size_t)(l * 2048 + foff + f)) * 512 + c) * 3 + k];
}
// conv2-weight repack: dst[o][k*1024+c'] = c2w[l][o][coff+c'][k]   (512x3072)
__global__ __launch_bounds__(256) void repack2(const float* __restrict__ src, float* __restrict__ dst,
                                               int l, int coff) {
  int idx = blockIdx.x * 256 + threadIdx.x;
  int o = idx / 3072, kk = idx % 3072;
  int k = kk / 1024, c = kk % 1024;
  dst[idx] = src[(((size_t)(l * 512 + o)) * 2048 + coff + c) * 3 + k];
}
__global__ __launch_bounds__(256) void repack_dp1(const float* __restrict__ src, float* __restrict__ dst) {
  int idx = blockIdx.x * 256 + threadIdx.x;
  int f = idx / 1536, kk = idx % 1536;
  int k = kk / 512, c = kk % 512;
  dst[idx] = src[((size_t)f * 512 + c) * 3 + k];
}
__global__ __launch_bounds__(256) void repack_dp2(const float* __restrict__ src, float* __restrict__ dst) {
  int idx = blockIdx.x * 256 + threadIdx.x;
  int f = idx / 768, kk = idx % 768;
  int k = kk / 256, c = kk % 256;
  dst[idx] = src[((size_t)f * 256 + c) * 3 + k];
}

__global__ __launch_bounds__(256) void dur_kf(const float* __restrict__ dp3, const float* __restrict__ pw,
                                              const float* __restrict__ pb, const int* __restrict__ lens,
                                              float* __restrict__ out) {
  int tid = threadIdx.x;
  int w = tid >> 6, lane = tid & 63;
  int row = blockIdx.x * 4 + w;
  int b = row >> 9, s = row & 511;
  size_t base = (size_t)(b * SP + s + 1) * 256;
  double sum = 0.0;
#pragma unroll
  for (int e = 0; e < 4; e++) {
    int c = lane + 64 * e;
    sum += (double)dp3[base + c] * (double)pw[c];
  }
  for (int o = 32; o; o >>= 1) sum += __shfl_down(sum, o);
  if (lane == 0) {
    double y = sum + (double)pb[0];
    double mval = (s >= lens[b]) ? 1.0 : 0.0;
    y *= mval;
    out[row] = (float)ceil(exp(y));
  }
}

// ---------------------------------------------------------------------------
extern "C" void kernel_launch(void* const* d_in, const int* in_sizes, int n_in,
                              void* d_out, int out_size, void* d_ws, size_t ws_size,
                              hipStream_t stream) {
  const int* xids = (const int*)d_in[0];
  const int* lens = (const int*)d_in[1];
  const float* emb  = (const float*)d_in[2];
  const float* Wq = (const float*)d_in[3];  const float* bq = (const float*)d_in[4];
  const float* Wk = (const float*)d_in[5];  const float* bk = (const float*)d_in[6];
  const float* Wv = (const float*)d_in[7];  const float* bv = (const float*)d_in[8];
  const float* Wo = (const float*)d_in[9];  const float* bo = (const float*)d_in[10];
  const float* c1w = (const float*)d_in[11]; const float* c1b = (const float*)d_in[12];
  const float* c2w = (const float*)d_in[13]; const float* c2b = (const float*)d_in[14];
  const float* ln1g = (const float*)d_in[15]; const float* ln1b = (const float*)d_in[16];
  const float* ln2g = (const float*)d_in[17]; const float* ln2b = (const float*)d_in[18];
  const float* pw = (const float*)d_in[19];  const float* pb = (const float*)d_in[20];
  const float* dpc1w = (const float*)d_in[21]; const float* dpc1b = (const float*)d_in[22];
  const float* dpln1g = (const float*)d_in[23]; const float* dpln1b = (const float*)d_in[24];
  const float* dpc2w = (const float*)d_in[25]; const float* dpc2b = (const float*)d_in[26];
  const float* dpln2g = (const float*)d_in[27]; const float* dpln2b = (const float*)d_in[28];
  const float* dppw = (const float*)d_in[29]; const float* dppb = (const float*)d_in[30];
  float* out = (float*)d_out;

  char* p = (char*)d_ws;
  float* xpad = (float*)p;  p += 33685504;   // (B,SP,512) f32
  float* qb = (float*)p;    p += 33554432;   // (B,S,512)
  float* kb = (float*)p;    p += 33554432;   //  -- doubles as t / dp scratch
  float* vb = (float*)p;    p += 33554432;
  float* midf = (float*)p;  p += 67371008;   // (B,SP,1024) conv half; aliased by dp stage
  float* w1t = (float*)p;   p += 6291456;    // (1024,1536)
  float* w2t = (float*)p;   p += 6291456;    // (512,3072)
  float* dpw1t = (float*)p; p += 1572864;    // (256,1536)
  float* dpw2t = (float*)p; p += 786432;     // (256,768)
  float* hm  = midf;                                   // (B,SP,512)
  float* dp2 = (float*)((char*)midf + 33685504);       // (B,SP,256)
  float* dp3 = (float*)((char*)midf + 33685504 + 16842752);

  zero_padf<<<128, 256, 0, stream>>>(xpad, 512);
  zero_padf<<<256, 256, 0, stream>>>(midf, 1024);
  embedf<<<16384, 256, 0, stream>>>(xids, emb, xpad);

  const long XB = (long)SP * 512;     // xpad batch stride
  const long QB = (long)512 * 512;    // qkv/t batch stride
  const long MB = (long)SP * 1024;    // midf batch stride

  for (int l = 0; l < 6; l++) {
    gemm_f32<0, false, false><<<dim3(256, 8), 256, 0, stream>>>(
        xpad, 512, XB, 1, Wq + (size_t)l * 262144, 512, bq + l * 512,
        qb, 512, QB, 0, 512, 512);
    gemm_f32<0, false, false><<<dim3(256, 8), 256, 0, stream>>>(
        xpad, 512, XB, 1, Wk + (size_t)l * 262144, 512, bk + l * 512,
        kb, 512, QB, 0, 512, 512);
    gemm_f32<0, false, false><<<dim3(256, 8), 256, 0, stream>>>(
        xpad, 512, XB, 1, Wv + (size_t)l * 262144, 512, bv + l * 512,
        vb, 512, QB, 0, 512, 512);
    ropef<<<16384, 256, 0, stream>>>(qb, kb);
    flashf<<<2048, 256, 0, stream>>>(qb, kb, vb, qb, lens);   // o in-place over q
    gemm_f32<0, false, false><<<dim3(256, 8), 256, 0, stream>>>(
        qb, 512, QB, 0, Wo + (size_t)l * 262144, 512, bo + l * 512,
        kb, 512, QB, 0, 512, 512);                             // t -> kb
    ln_resf<<<16384, 256, 0, stream>>>(xpad, kb, ln1g + l * 512, ln1b + l * 512);
    repack1<<<6144, 256, 0, stream>>>(c1w, w1t, l, 0);
    gemm_f32<0, true, false><<<dim3(256, 16), 256, 0, stream>>>(
        xpad, 512, XB, 0, w1t, 1536, c1b + l * 2048 + 0,
        midf, 1024, MB, 1, 1024, 1536);
    repack2<<<6144, 256, 0, stream>>>(c2w, w2t, l, 0);
    gemm_f32<0, false, false><<<dim3(256, 8), 256, 0, stream>>>(
        midf, 1024, MB, 0, w2t, 3072, c2b + l * 512,
        kb, 512, QB, 0, 512, 3072);
    repack1<<<6144, 256, 0, stream>>>(c1w, w1t, l, 1024);
    gemm_f32<0, true, false><<<dim3(256, 16), 256, 0, stream>>>(
        xpad, 512, XB, 0, w1t, 1536, c1b + l * 2048 + 1024,
        midf, 1024, MB, 1, 1024, 1536);
    repack2<<<6144, 256, 0, stream>>>(c2w, w2t, l, 1024);
    gemm_f32<0, false, true><<<dim3(256, 8), 256, 0, stream>>>(
        midf, 1024, MB, 0, w2t, 3072, c2b + l * 512,
        kb, 512, QB, 0, 512, 3072);
    ln_resf<<<16384, 256, 0, stream>>>(xpad, kb, ln2g + l * 512, ln2b + l * 512);
  }

  // mu projection: N=80, scatter to (B,80,S) f32
  gemm_f32<2, false, false><<<dim3(256, 2), 256, 0, stream>>>(
      xpad, 512, XB, 1, pw, 512, pb, out, 0, 0, 0, 80, 512);

  // duration predictor (tiled f64-accum convs, f64 LN)
  zero_padf<<<128, 256, 0, stream>>>(hm, 512);
  zero_padf<<<64, 256, 0, stream>>>(dp2, 256);
  zero_padf<<<64, 256, 0, stream>>>(dp3, 256);
  maskhf<<<16384, 256, 0, stream>>>(xpad, hm, lens);
  repack_dp1<<<1536, 256, 0, stream>>>(dpc1w, dpw1t);
  repack_dp2<<<768, 256, 0, stream>>>(dpc2w, dpw2t);
  gemm_dp64<true><<<dim3(256, 4), 256, 0, stream>>>(
      hm, 512, XB, 0, dpw1t, 1536, dpc1b, kb, 256, (long)512 * 256, 256, 1536);
  dplnf<<<16384, 256, 0, stream>>>(kb, dp2, dpln1g, dpln1b, lens);
  gemm_dp64<true><<<dim3(256, 4), 256, 0, stream>>>(
      dp2, 256, (long)SP * 256, 0, dpw2t, 768, dpc2b, kb, 256, (long)512 * 256, 256, 768);
  dplnf<<<16384, 256, 0, stream>>>(kb, dp3, dpln2g, dpln2b, lens);
  dur_kf<<<4096, 256, 0, stream>>>(dp3, dppw, dppb, lens, out + 1310720);
}